// Round 8
// baseline (6115.813 us; speedup 1.0000x reference)
//
#include <hip/hip_runtime.h>
#include <math.h>

#define E_DIM 768
#define NTOK 1025
#define B_DIM 32
#define NHEADS 12
#define HDIM 64
#define LAYERS 12
#define FF_DIM 3072
#define P2 576
#define GRID 384

// ---------------- helpers ----------------
__device__ __forceinline__ float block_reduce_sum(float v, float* red) {
  int tid = threadIdx.x;
  red[tid] = v;
  __syncthreads();
#pragma unroll
  for (int s = 128; s > 0; s >>= 1) {
    if (tid < s) red[tid] += red[tid + s];
    __syncthreads();
  }
  float r = red[0];
  __syncthreads();
  return r;
}

__device__ __forceinline__ unsigned aload(unsigned* p) {
  return __hip_atomic_load(p, __ATOMIC_RELAXED, __HIP_MEMORY_SCOPE_AGENT);
}
__device__ __forceinline__ void astore(unsigned* p, unsigned v) {
  __hip_atomic_store(p, v, __ATOMIC_RELAXED, __HIP_MEMORY_SCOPE_AGENT);
}

// grid barrier: distributed arrival flags (plain stores), master scans with
// read-only loads, broadcasts 'go'. No RMW anywhere -> no LLC atomic queue.
// Release: all-thread threadfence before arrival. Acquire: threadfence after.
__device__ __forceinline__ void grid_barrier(unsigned* flags, unsigned* go,
                                             unsigned gen, int bid) {
  __threadfence();      // release: every thread's stores written back device-wide
  __syncthreads();
  int tid = threadIdx.x;
  if (bid == 0) {
    if (tid == 0) astore(&flags[0], gen);
    unsigned it = 0;
    int ok;
    do {
      int mine = 1;
      if (tid < GRID && aload(&flags[tid]) < gen) mine = 0;
      if (tid + 256 < GRID && aload(&flags[tid + 256]) < gen) mine = 0;
      ok = __syncthreads_and(mine);
      if (++it > 200000u) break;  // fail loud, not hang
    } while (!ok);
    if (tid == 0) astore(go, gen);
  } else {
    if (tid == 0) {
      astore(&flags[bid], gen);
      unsigned it = 0;
      while (aload(go) < gen) {     // read-only poll: line shared, no ping-pong
        if (++it > 200000u) break;
        __builtin_amdgcn_s_sleep(1);
      }
    }
    __syncthreads();
  }
  __threadfence();      // acquire: invalidate stale cached lines
}

// ---------------- setup kernels (unchanged, proven) ----------------
__global__ __launch_bounds__(256) void embed_gemm(
    const float* __restrict__ A, const float* __restrict__ W,
    const float* __restrict__ bias, const float* __restrict__ pos,
    float* __restrict__ scene) {
  __shared__ float Xs[16][132];
  __shared__ float Ws[16][132];
  int tid = threadIdx.x;
  int n0 = blockIdx.x * 128;
  int m0 = blockIdx.y * 128;
  int lr = tid >> 2;
  int lk = (tid & 3) << 2;
  int ty = tid >> 4, tx = tid & 15;
  float acc[8][8] = {};
  for (int k0 = 0; k0 < P2; k0 += 16) {
    float4 x0 = *(const float4*)(A + (size_t)(m0 + lr) * P2 + k0 + lk);
    float4 x1 = *(const float4*)(A + (size_t)(m0 + 64 + lr) * P2 + k0 + lk);
    float4 w0 = *(const float4*)(W + (size_t)(n0 + lr) * P2 + k0 + lk);
    float4 w1 = *(const float4*)(W + (size_t)(n0 + 64 + lr) * P2 + k0 + lk);
    __syncthreads();
    Xs[lk + 0][lr] = x0.x; Xs[lk + 1][lr] = x0.y; Xs[lk + 2][lr] = x0.z; Xs[lk + 3][lr] = x0.w;
    Xs[lk + 0][64 + lr] = x1.x; Xs[lk + 1][64 + lr] = x1.y; Xs[lk + 2][64 + lr] = x1.z; Xs[lk + 3][64 + lr] = x1.w;
    Ws[lk + 0][lr] = w0.x; Ws[lk + 1][lr] = w0.y; Ws[lk + 2][lr] = w0.z; Ws[lk + 3][lr] = w0.w;
    Ws[lk + 0][64 + lr] = w1.x; Ws[lk + 1][64 + lr] = w1.y; Ws[lk + 2][64 + lr] = w1.z; Ws[lk + 3][64 + lr] = w1.w;
    __syncthreads();
#pragma unroll
    for (int kk = 0; kk < 16; ++kk) {
      float4 a0 = *(const float4*)&Xs[kk][ty << 2];
      float4 a1 = *(const float4*)&Xs[kk][64 + (ty << 2)];
      float4 b0 = *(const float4*)&Ws[kk][tx << 2];
      float4 b1 = *(const float4*)&Ws[kk][64 + (tx << 2)];
      float av[8] = {a0.x, a0.y, a0.z, a0.w, a1.x, a1.y, a1.z, a1.w};
      float bv[8] = {b0.x, b0.y, b0.z, b0.w, b1.x, b1.y, b1.z, b1.w};
#pragma unroll
      for (int i = 0; i < 8; ++i)
#pragma unroll
        for (int j = 0; j < 8; ++j) acc[i][j] += av[i] * bv[j];
    }
  }
#pragma unroll
  for (int i = 0; i < 8; ++i) {
    int mloc = (i < 4) ? ((ty << 2) + i) : (64 + (ty << 2) + i - 4);
    int m = m0 + mloc;
    int b = m >> 10, nt = m & 1023;
    size_t row = ((size_t)b * NTOK + 1 + nt) * E_DIM;
    size_t prow = (size_t)(1 + nt) * E_DIM;
#pragma unroll
    for (int half = 0; half < 2; ++half) {
      int n = n0 + half * 64 + (tx << 2);
      float4 o4;
      o4.x = acc[i][half * 4 + 0] + bias[n + 0] + pos[prow + n + 0];
      o4.y = acc[i][half * 4 + 1] + bias[n + 1] + pos[prow + n + 1];
      o4.z = acc[i][half * 4 + 2] + bias[n + 2] + pos[prow + n + 2];
      o4.w = acc[i][half * 4 + 3] + bias[n + 3] + pos[prow + n + 3];
      *(float4*)&scene[row + n] = o4;
    }
  }
}

__global__ void scene_cls(const float* __restrict__ cls, const float* __restrict__ pos,
                          float* __restrict__ scene) {
  int b = blockIdx.x;
  for (int e = threadIdx.x; e < E_DIM; e += 256)
    scene[(size_t)b * NTOK * E_DIM + e] = cls[e] + pos[e];
}

__global__ __launch_bounds__(256) void ln_rows(const float* __restrict__ in, float* __restrict__ out) {
  __shared__ float red[256];
  int r = blockIdx.x, tid = threadIdx.x;
  const float* x = in + (size_t)r * E_DIM;
  float a0 = x[tid], a1 = x[tid + 256], a2 = x[tid + 512];
  float mean = block_reduce_sum(a0 + a1 + a2, red) * (1.f / 768.f);
  float d0 = a0 - mean, d1 = a1 - mean, d2 = a2 - mean;
  float var = block_reduce_sum(d0 * d0 + d1 * d1 + d2 * d2, red) * (1.f / 768.f);
  float rinv = rsqrtf(var + 1e-5f);
  float* o = out + (size_t)r * E_DIM;
  o[tid] = d0 * rinv; o[tid + 256] = d1 * rinv; o[tid + 512] = d2 * rinv;
}

__global__ __launch_bounds__(256) void tgt_init(
    const float* __restrict__ tmask, const float* __restrict__ W,
    const float* __restrict__ bias, const float* __restrict__ cls,
    const float* __restrict__ tpos, float* __restrict__ tq) {
  int b = blockIdx.x, tid = threadIdx.x;
  for (int e = tid; e < E_DIM; e += 256)
    tq[(size_t)(b * 2) * E_DIM + e] = cls[e] + tpos[e];
  const float* tm = tmask + (size_t)b * P2;
  for (int e = tid; e < E_DIM; e += 256) {
    const float* wr = W + (size_t)e * P2;
    float s = 0.f;
    for (int k = 0; k < P2; k += 4) {
      float4 w4 = *(const float4*)&wr[k];
      float4 t4 = *(const float4*)&tm[k];
      s += w4.x * t4.x + w4.y * t4.y + w4.z * t4.z + w4.w * t4.w;
    }
    tq[(size_t)(b * 2 + 1) * E_DIM + e] = s + bias[e] + tpos[E_DIM + e];
  }
}

__global__ void prep_m(const float* __restrict__ Wq, const float* __restrict__ Wk,
                       float* __restrict__ Mb) {
  int l = blockIdx.y;
  int idx = blockIdx.x * 256 + threadIdx.x;
  int d = idx >> 6, dp = idx & 63;
  const float* wq = Wq + l * 4096;
  const float* wk = Wk + l * 4096;
  float s = 0.f;
#pragma unroll 8
  for (int e = 0; e < 64; ++e) s += wq[e * 64 + d] * wk[e * 64 + dp];
  Mb[l * 4096 + idx] = s;
}

__global__ void prep_wvo(const float* __restrict__ Wv, const float* __restrict__ Wo,
                         float* __restrict__ Wvo) {
  int l = blockIdx.y;
  int idx = blockIdx.x * 256 + threadIdx.x;
  int ep = idx / 768, hd = idx % 768;
  int h = hd >> 6, d = hd & 63;
  const float* wv = Wv + (size_t)l * 4096;
  const float* wo = Wo + (size_t)l * 768 * 768 + (size_t)ep * 768 + h * 64;
  float s = 0.f;
#pragma unroll 8
  for (int ev = 0; ev < 64; ++ev) s += wv[ev * 64 + d] * wo[ev];
  Wvo[(size_t)l * 589824 + idx] = s;
}

// ---------------- shared-memory stage structs ----------------
struct GemmS { float Xs[16][64]; float Ws[16][64]; };
struct AttnS { float red[256]; float sred[2][16]; float cred[2][16][64]; };
struct LnS   { float red[256]; float q[768]; float qm[768]; };
struct TopS  { float v[1024]; float bv[256]; int bi[256]; };

// ---------------- device stage functions ----------------
__device__ void dev_qproj(LnS& L, int m, const float* gl, const float* bl,
                          const float* M, float* qMg, float* qMb) {
  int tid = threadIdx.x;
  const float inv_scale = rsqrtf(768.f);
  for (int o = tid; o < 768; o += 256) {
    int h = o >> 6, dp = o & 63;
    const float* qh = L.q + h * 64;
    float s = 0.f;
#pragma unroll 8
    for (int d = 0; d < 64; ++d) s += qh[d] * M[d * 64 + dp];
    L.qm[o] = s;
    qMg[(size_t)m * E_DIM + o] = s * gl[o] * inv_scale;
  }
  __syncthreads();
  if (tid < NHEADS) {
    float acc = 0.f;
#pragma unroll 8
    for (int dp = 0; dp < 64; ++dp) acc += L.qm[tid * 64 + dp] * bl[tid * 64 + dp];
    qMb[m * NHEADS + tid] = acc * inv_scale;
  }
}

__device__ void dev_qln0(LnS& L, int m, const float* tq, const float* g1,
                         const float* b1, const float* Mb, float* qMg, float* qMb) {
  int tid = threadIdx.x;
  const float* x = tq + (size_t)m * E_DIM;
  float a0 = x[tid], a1 = x[tid + 256], a2 = x[tid + 512];
  float mean = block_reduce_sum(a0 + a1 + a2, L.red) * (1.f / 768.f);
  float d0 = a0 - mean, d1 = a1 - mean, d2 = a2 - mean;
  float var = block_reduce_sum(d0 * d0 + d1 * d1 + d2 * d2, L.red) * (1.f / 768.f);
  float rinv = rsqrtf(var + 1e-5f);
  L.q[tid] = d0 * rinv * g1[tid] + b1[tid];
  L.q[tid + 256] = d1 * rinv * g1[tid + 256] + b1[tid + 256];
  L.q[tid + 512] = d2 * rinv * g1[tid + 512] + b1[tid + 512];
  __syncthreads();
  dev_qproj(L, m, g1, b1, Mb, qMg, qMb);
}

#define ACH 272
__device__ void dev_attn(AttnS& A, const float* __restrict__ ns,
                         const float* __restrict__ qMg, const float* __restrict__ qMb,
                         const float* __restrict__ g1, const float* __restrict__ b1,
                         int l, float* __restrict__ ctx, int bid) {
  int b = bid / NHEADS;
  int h = bid % NHEADS;
  int tid = threadIdx.x;
  int g = tid >> 4;
  int lane = tid & 15;
  int r0 = b * 2, r1 = r0 + 1;
  const float* nsb = ns + (size_t)b * NTOK * E_DIM + h * 64;
  float4 q0v = *(const float4*)(qMg + (size_t)r0 * E_DIM + h * 64 + lane * 4);
  float4 q1v = *(const float4*)(qMg + (size_t)r1 * E_DIM + h * 64 + lane * 4);
  float qb0 = qMb[r0 * NHEADS + h], qb1 = qMb[r1 * NHEADS + h];
  float m = -1e30f, s0 = 0.f, s1 = 0.f;
  float4 c0 = {0, 0, 0, 0}, c1 = {0, 0, 0, 0};
  float4 v[17];
  float e0a[17], e1a[17];
  for (int cb = 0; cb < NTOK; cb += ACH) {
    int ntk = NTOK - cb; if (ntk > ACH) ntk = ACH;
    int cnt = (ntk - g + 15) >> 4;
    float mloc = -1e30f;
#pragma unroll
    for (int i = 0; i < 17; ++i) {
      if (i < cnt) {
        int k = cb + g + (i << 4);
        float4 vv = *(const float4*)(nsb + (size_t)k * E_DIM + lane * 4);
        v[i] = vv;
        float p0 = vv.x * q0v.x + vv.y * q0v.y + vv.z * q0v.z + vv.w * q0v.w;
        float p1 = vv.x * q1v.x + vv.y * q1v.y + vv.z * q1v.z + vv.w * q1v.w;
#pragma unroll
        for (int off = 8; off; off >>= 1) {
          p0 += __shfl_xor(p0, off, 16);
          p1 += __shfl_xor(p1, off, 16);
        }
        float e0 = p0 + qb0, e1 = p1 + qb1;
        e0a[i] = e0; e1a[i] = e1;
        mloc = fmaxf(mloc, fmaxf(e0, e1));
      }
    }
    A.red[tid] = mloc;
    __syncthreads();
#pragma unroll
    for (int s = 128; s > 0; s >>= 1) {
      if (tid < s) A.red[tid] = fmaxf(A.red[tid], A.red[tid + s]);
      __syncthreads();
    }
    float mnew = fmaxf(m, A.red[0]);
    __syncthreads();
    if (mnew > m) {
      float f = expf(m - mnew);
      s0 *= f; s1 *= f;
      c0.x *= f; c0.y *= f; c0.z *= f; c0.w *= f;
      c1.x *= f; c1.y *= f; c1.z *= f; c1.w *= f;
      m = mnew;
    }
#pragma unroll
    for (int i = 0; i < 17; ++i) {
      if (i < cnt) {
        float p0 = expf(e0a[i] - m);
        float p1 = expf(e1a[i] - m);
        s0 += p0; s1 += p1;
        c0.x += p0 * v[i].x; c0.y += p0 * v[i].y; c0.z += p0 * v[i].z; c0.w += p0 * v[i].w;
        c1.x += p1 * v[i].x; c1.y += p1 * v[i].y; c1.z += p1 * v[i].z; c1.w += p1 * v[i].w;
      }
    }
  }
  if (lane == 0) { A.sred[0][g] = s0; A.sred[1][g] = s1; }
  *(float4*)&A.cred[0][g][lane * 4] = c0;
  *(float4*)&A.cred[1][g][lane * 4] = c1;
  __syncthreads();
  if (tid < 128) {
    int t = tid >> 6, dd = tid & 63;
    int o = h * 64 + dd;
    float stot = 0.f, cs = 0.f;
#pragma unroll
    for (int gg = 0; gg < 16; ++gg) { stot += A.sred[t][gg]; cs += A.cred[t][gg][dd]; }
    float inv = 1.f / stot;
    ctx[(size_t)(r0 + t) * E_DIM + o] = cs * inv * g1[l * E_DIM + o] + b1[l * E_DIM + o];
  }
}

// skinny GEMM tile; optional epilogue bias(+relu) for full-K direct output
__device__ void dev_skinny(GemmS& G, const float* X, int K, const float* W,
                           int kchunk, float* part, int N, int n0, int s,
                           const float* bias, int relu) {
  int tid = threadIdx.x;
  int kbeg = s * kchunk;
  int lr = tid >> 2;
  int lk = (tid & 3) << 2;
  int ty = tid >> 4, tx = tid & 15;
  float acc[4][4] = {};
  for (int k0 = kbeg; k0 < kbeg + kchunk; k0 += 16) {
    float4 xv = *(const float4*)(X + (size_t)lr * K + k0 + lk);
    float4 wv = *(const float4*)(W + (size_t)(n0 + lr) * K + k0 + lk);
    __syncthreads();
    G.Xs[lk + 0][lr] = xv.x; G.Xs[lk + 1][lr] = xv.y; G.Xs[lk + 2][lr] = xv.z; G.Xs[lk + 3][lr] = xv.w;
    G.Ws[lk + 0][lr] = wv.x; G.Ws[lk + 1][lr] = wv.y; G.Ws[lk + 2][lr] = wv.z; G.Ws[lk + 3][lr] = wv.w;
    __syncthreads();
#pragma unroll
    for (int kk = 0; kk < 16; ++kk) {
      float4 a4 = *(const float4*)&G.Xs[kk][ty << 2];
      float4 b4 = *(const float4*)&G.Ws[kk][tx << 2];
      float av[4] = {a4.x, a4.y, a4.z, a4.w};
      float bv[4] = {b4.x, b4.y, b4.z, b4.w};
#pragma unroll
      for (int i = 0; i < 4; ++i)
#pragma unroll
        for (int j = 0; j < 4; ++j) acc[i][j] += av[i] * bv[j];
    }
  }
#pragma unroll
  for (int i = 0; i < 4; ++i) {
    int mm = (ty << 2) + i;
    float4 o4 = make_float4(acc[i][0], acc[i][1], acc[i][2], acc[i][3]);
    if (bias) {
      int n = n0 + (tx << 2);
      o4.x += bias[n + 0]; o4.y += bias[n + 1]; o4.z += bias[n + 2]; o4.w += bias[n + 3];
      if (relu) {
        o4.x = fmaxf(o4.x, 0.f); o4.y = fmaxf(o4.y, 0.f);
        o4.z = fmaxf(o4.z, 0.f); o4.w = fmaxf(o4.w, 0.f);
      }
    }
    *(float4*)&part[((size_t)s * 64 + mm) * N + n0 + (tx << 2)] = o4;
  }
}

__device__ void dev_reduce_ln_q(LnS& L, const float* part, int S, const float* bias,
                                const float* res, const float* g, const float* bsh,
                                float* out, const float* Mb_next, const float* g1n,
                                const float* b1n, float* qMg, float* qMb,
                                float* xmean, int m) {
  int tid = threadIdx.x;
  float t[3];
#pragma unroll
  for (int c = 0; c < 3; ++c) {
    int n = tid + c * 256;
    float s = 0.f;
    for (int i = 0; i < S; ++i) s += part[((size_t)i * 64 + m) * 768 + n];
    t[c] = s + bias[n] + res[(size_t)m * 768 + n];
  }
  float mean = block_reduce_sum(t[0] + t[1] + t[2], L.red) * (1.f / 768.f);
  float d0 = t[0] - mean, d1 = t[1] - mean, d2 = t[2] - mean;
  float var = block_reduce_sum(d0 * d0 + d1 * d1 + d2 * d2, L.red) * (1.f / 768.f);
  float rinv = rsqrtf(var + 1e-5f);
  float y0 = d0 * rinv * g[tid] + bsh[tid];
  float y1 = d1 * rinv * g[tid + 256] + bsh[tid + 256];
  float y2 = d2 * rinv * g[tid + 512] + bsh[tid + 512];
  out[(size_t)m * 768 + tid] = y0;
  out[(size_t)m * 768 + tid + 256] = y1;
  out[(size_t)m * 768 + tid + 512] = y2;
  if (xmean) {
    float* xr = xmean + (size_t)(m >> 1) * 768;
    atomicAdd(&xr[tid], 0.5f * y0);
    atomicAdd(&xr[tid + 256], 0.5f * y1);
    atomicAdd(&xr[tid + 512], 0.5f * y2);
  }
  if (Mb_next) {
    float mean2 = block_reduce_sum(y0 + y1 + y2, L.red) * (1.f / 768.f);
    float e0 = y0 - mean2, e1 = y1 - mean2, e2 = y2 - mean2;
    float var2 = block_reduce_sum(e0 * e0 + e1 * e1 + e2 * e2, L.red) * (1.f / 768.f);
    float rinv2 = rsqrtf(var2 + 1e-5f);
    L.q[tid] = e0 * rinv2 * g1n[tid] + b1n[tid];
    L.q[tid + 256] = e1 * rinv2 * g1n[tid + 256] + b1n[tid + 256];
    L.q[tid + 512] = e2 * rinv2 * g1n[tid + 512] + b1n[tid + 512];
    __syncthreads();
    dev_qproj(L, m, g1n, b1n, Mb_next, qMg, qMb);
  }
}

__device__ void dev_top5(TopS& T, const float* logits, const float* bias,
                         float* out, int b) {
  int tid = threadIdx.x;
  for (int i = tid; i < 1024; i += 256)
    T.v[i] = logits[(size_t)b * 1024 + i] + bias[i];
  float* ob = out + (size_t)b * 5 * NTOK;
  for (int i = tid; i < 5 * NTOK; i += 256) ob[i] = 0.f;
  __syncthreads();
  for (int it = 0; it < 5; ++it) {
    float best = -1e38f;
    int bidx = 0x7fffffff;
    for (int i = tid; i < 1024; i += 256) {
      float x = T.v[i];
      if (x > best || (x == best && i < bidx)) { best = x; bidx = i; }
    }
    T.bv[tid] = best; T.bi[tid] = bidx;
    __syncthreads();
    for (int s = 128; s > 0; s >>= 1) {
      if (tid < s) {
        if (T.bv[tid + s] > T.bv[tid] ||
            (T.bv[tid + s] == T.bv[tid] && T.bi[tid + s] < T.bi[tid])) {
          T.bv[tid] = T.bv[tid + s]; T.bi[tid] = T.bi[tid + s];
        }
      }
      __syncthreads();
    }
    if (tid == 0) {
      ob[it * NTOK + T.bi[0]] = 1.0f;
      T.v[T.bi[0]] = -1e38f;
    }
    __syncthreads();
  }
}

// ---------------- persistent mega kernel ----------------
struct MegaArgs {
  const float* scene;
  const float* Mbuf; const float* Wvo;
  const float* ln1_g; const float* ln1_b; const float* ln2_g; const float* ln2_b;
  const float* bo; const float* W1; const float* fb1; const float* W2; const float* fb2;
  const float* mlp_W; const float* mlp_b;
  float* tq; float* qMg; float* qMb; float* ctx; float* xbuf; float* h1;
  float* xm; float* partA; float* out;
  unsigned* flags; unsigned* go;
};

__global__ __launch_bounds__(256, 2) void mega(MegaArgs P) {
  __shared__ __align__(16) float smem_raw[2432];
  GemmS& G = *(GemmS*)smem_raw;
  AttnS& A = *(AttnS*)smem_raw;
  LnS& L = *(LnS*)smem_raw;
  TopS& T = *(TopS*)smem_raw;
  int bid = blockIdx.x;
  unsigned gen = 0;
#define GBAR() do { ++gen; grid_barrier(P.flags, P.go, gen, bid); } while (0)

  // layer-0 q projection
  if (bid < 64)
    dev_qln0(L, bid, P.tq, P.ln1_g, P.ln1_b, P.Mbuf, P.qMg, P.qMb);
  GBAR();

  for (int l = 0; l < LAYERS; ++l) {
    // 1. attention (all 384 blocks)
    dev_attn(A, P.scene, P.qMg, P.qMb, P.ln1_g, P.ln1_b, l, P.ctx, bid);
    GBAR();
    // 2. out-proj full-K: 12 n-tiles, raw -> partA[64][768]
    if (bid < 12)
      dev_skinny(G, P.ctx, 768, P.Wvo + (size_t)l * 589824, 768, P.partA, 768,
                 bid * 64, 0, nullptr, 0);
    GBAR();
    // 3. x = LN1(proj + bo + tq)
    if (bid < 64)
      dev_reduce_ln_q(L, P.partA, 1, P.bo + l * 768, P.tq,
                      P.ln1_g + l * 768, P.ln1_b + l * 768, P.xbuf,
                      nullptr, nullptr, nullptr, nullptr, nullptr, nullptr, bid);
    GBAR();
    // 4. FF1 full-K with fused bias+relu -> h1[64][3072]
    if (bid < 48)
      dev_skinny(G, P.xbuf, 768, P.W1 + (size_t)l * FF_DIM * 768, 768, P.h1,
                 FF_DIM, bid * 64, 0, P.fb1 + l * FF_DIM, 1);
    GBAR();
    // 5. FF2 partials: 12 n-tiles x 4 k-chunks(768) -> partA (S=4)
    if (bid < 48)
      dev_skinny(G, P.h1, FF_DIM, P.W2 + (size_t)l * 768 * FF_DIM, 768, P.partA,
                 768, (bid % 12) * 64, bid / 12, nullptr, 0);
    GBAR();
    // 6. tq' = LN2(ff2 + b2 + x) [+ next qproj | + xm accumulate at l=11]
    if (bid < 64) {
      if (l < LAYERS - 1)
        dev_reduce_ln_q(L, P.partA, 4, P.fb2 + l * 768, P.xbuf,
                        P.ln2_g + l * 768, P.ln2_b + l * 768, P.tq,
                        P.Mbuf + (l + 1) * 4096, P.ln1_g + (l + 1) * 768,
                        P.ln1_b + (l + 1) * 768, P.qMg, P.qMb, nullptr, bid);
      else
        dev_reduce_ln_q(L, P.partA, 4, P.fb2 + l * 768, P.xbuf,
                        P.ln2_g + l * 768, P.ln2_b + l * 768, P.tq,
                        nullptr, nullptr, nullptr, nullptr, nullptr, P.xm, bid);
    }
    GBAR();
  }

  // head GEMM full-K: 16 n-tiles -> partA[64][1024]
  if (bid < 16)
    dev_skinny(G, P.xm, 768, P.mlp_W, 768, P.partA, 1024, bid * 64, 0, nullptr, 0);
  GBAR();
  if (bid < 32)
    dev_top5(T, P.partA, P.mlp_b, P.out, bid);
#undef GBAR
}

extern "C" void kernel_launch(void* const* d_in, const int* in_sizes, int n_in,
                              void* d_out, int out_size, void* d_ws, size_t ws_size,
                              hipStream_t stream) {
  const float* scene_masks = (const float*)d_in[0];
  const float* target_mask = (const float*)d_in[1];
  const float* emb_W = (const float*)d_in[2];
  const float* emb_b = (const float*)d_in[3];
  const float* class_embed = (const float*)d_in[4];
  const float* scene_pos = (const float*)d_in[5];
  const float* target_pos = (const float*)d_in[6];
  const float* ln1_g = (const float*)d_in[7];
  const float* ln1_b = (const float*)d_in[8];
  const float* ln2_g = (const float*)d_in[9];
  const float* ln2_b = (const float*)d_in[10];
  const float* Wq = (const float*)d_in[11];
  const float* Wk = (const float*)d_in[12];
  const float* Wv = (const float*)d_in[13];
  const float* Wo = (const float*)d_in[14];
  const float* bo = (const float*)d_in[15];
  const float* W1 = (const float*)d_in[16];
  const float* fb1 = (const float*)d_in[17];
  const float* W2 = (const float*)d_in[18];
  const float* fb2 = (const float*)d_in[19];
  const float* mlp_W = (const float*)d_in[20];
  const float* mlp_b = (const float*)d_in[21];
  float* out = (float*)d_out;

  float* ws = (float*)d_ws;
  float* scene = ws;                       // 25190400
  float* Mbuf = scene + 25190400;          // 49152
  float* Wvo = Mbuf + 49152;               // 7077888
  float* tq = Wvo + 7077888;               // 49152
  float* qMg = tq + 49152;                 // 49152
  float* qMb = qMg + 49152;                // 768
  float* ctxf = qMb + 768;                 // 49152
  float* xbuf = ctxf + 49152;              // 49152
  float* h1 = xbuf + 49152;                // 196608 (64x3072)
  float* xm = h1 + 196608;                 // 49152 (64x768, zeroed)
  float* partA = xm + 49152;               // 786432
  unsigned* flags = (unsigned*)(partA + 786432);  // 512 words
  unsigned* go = flags + 512;

  // ---- setup ----
  embed_gemm<<<dim3(6, 256), 256, 0, stream>>>(scene_masks, emb_W, emb_b, scene_pos, scene);
  scene_cls<<<32, 256, 0, stream>>>(class_embed, scene_pos, scene);
  ln_rows<<<32 * NTOK, 256, 0, stream>>>(scene, scene);
  tgt_init<<<32, 256, 0, stream>>>(target_mask, emb_W, emb_b, class_embed, target_pos, tq);
  prep_m<<<dim3(16, 12), 256, 0, stream>>>(Wq, Wk, Mbuf);
  prep_wvo<<<dim3(2304, 12), 256, 0, stream>>>(Wv, Wo, Wvo);
  hipMemsetAsync(xm, 0, 49152 * sizeof(float), stream);
  hipMemsetAsync(flags, 0, 520 * sizeof(unsigned), stream);

  // ---- persistent mega: 12 layers + head ----
  MegaArgs ma;
  ma.scene = scene;
  ma.Mbuf = Mbuf; ma.Wvo = Wvo;
  ma.ln1_g = ln1_g; ma.ln1_b = ln1_b; ma.ln2_g = ln2_g; ma.ln2_b = ln2_b;
  ma.bo = bo; ma.W1 = W1; ma.fb1 = fb1; ma.W2 = W2; ma.fb2 = fb2;
  ma.mlp_W = mlp_W; ma.mlp_b = mlp_b;
  ma.tq = tq; ma.qMg = qMg; ma.qMb = qMb; ma.ctx = ctxf; ma.xbuf = xbuf;
  ma.h1 = h1; ma.xm = xm; ma.partA = partA; ma.out = out;
  ma.flags = flags; ma.go = go;
  mega<<<GRID, 256, 0, stream>>>(ma);
}

// Round 10
// 5115.613 us; speedup vs baseline: 1.1955x; 1.1955x over previous
//
#include <hip/hip_runtime.h>
#include <math.h>

#define E_DIM 768
#define NTOK 1025
#define B_DIM 32
#define NHEADS 12
#define HDIM 64
#define LAYERS 12
#define FF_DIM 3072
#define P2 576

// ---------------- helpers ----------------
__device__ __forceinline__ float block_reduce_sum(float v, float* red) {
  int tid = threadIdx.x;
  red[tid] = v;
  __syncthreads();
#pragma unroll
  for (int s = 128; s > 0; s >>= 1) {
    if (tid < s) red[tid] += red[tid + s];
    __syncthreads();
  }
  float r = red[0];
  __syncthreads();
  return r;
}

// ---------------- embed GEMM: 128x128 tile, 8x8 acc/thread ----------------
__global__ __launch_bounds__(256) void embed_gemm(
    const float* __restrict__ A, const float* __restrict__ W,
    const float* __restrict__ bias, const float* __restrict__ pos,
    float* __restrict__ scene) {
  __shared__ float Xs[16][132];
  __shared__ float Ws[16][132];
  int tid = threadIdx.x;
  int n0 = blockIdx.x * 128;
  int m0 = blockIdx.y * 128;
  int lr = tid >> 2;
  int lk = (tid & 3) << 2;
  int ty = tid >> 4, tx = tid & 15;
  float acc[8][8] = {};
  for (int k0 = 0; k0 < P2; k0 += 16) {
    float4 x0 = *(const float4*)(A + (size_t)(m0 + lr) * P2 + k0 + lk);
    float4 x1 = *(const float4*)(A + (size_t)(m0 + 64 + lr) * P2 + k0 + lk);
    float4 w0 = *(const float4*)(W + (size_t)(n0 + lr) * P2 + k0 + lk);
    float4 w1 = *(const float4*)(W + (size_t)(n0 + 64 + lr) * P2 + k0 + lk);
    __syncthreads();
    Xs[lk + 0][lr] = x0.x; Xs[lk + 1][lr] = x0.y; Xs[lk + 2][lr] = x0.z; Xs[lk + 3][lr] = x0.w;
    Xs[lk + 0][64 + lr] = x1.x; Xs[lk + 1][64 + lr] = x1.y; Xs[lk + 2][64 + lr] = x1.z; Xs[lk + 3][64 + lr] = x1.w;
    Ws[lk + 0][lr] = w0.x; Ws[lk + 1][lr] = w0.y; Ws[lk + 2][lr] = w0.z; Ws[lk + 3][lr] = w0.w;
    Ws[lk + 0][64 + lr] = w1.x; Ws[lk + 1][64 + lr] = w1.y; Ws[lk + 2][64 + lr] = w1.z; Ws[lk + 3][64 + lr] = w1.w;
    __syncthreads();
#pragma unroll
    for (int kk = 0; kk < 16; ++kk) {
      float4 a0 = *(const float4*)&Xs[kk][ty << 2];
      float4 a1 = *(const float4*)&Xs[kk][64 + (ty << 2)];
      float4 b0 = *(const float4*)&Ws[kk][tx << 2];
      float4 b1 = *(const float4*)&Ws[kk][64 + (tx << 2)];
      float av[8] = {a0.x, a0.y, a0.z, a0.w, a1.x, a1.y, a1.z, a1.w};
      float bv[8] = {b0.x, b0.y, b0.z, b0.w, b1.x, b1.y, b1.z, b1.w};
#pragma unroll
      for (int i = 0; i < 8; ++i)
#pragma unroll
        for (int j = 0; j < 8; ++j) acc[i][j] += av[i] * bv[j];
    }
  }
#pragma unroll
  for (int i = 0; i < 8; ++i) {
    int mloc = (i < 4) ? ((ty << 2) + i) : (64 + (ty << 2) + i - 4);
    int m = m0 + mloc;
    int b = m >> 10, nt = m & 1023;
    size_t row = ((size_t)b * NTOK + 1 + nt) * E_DIM;
    size_t prow = (size_t)(1 + nt) * E_DIM;
#pragma unroll
    for (int half = 0; half < 2; ++half) {
      int n = n0 + half * 64 + (tx << 2);
      float4 o4;
      o4.x = acc[i][half * 4 + 0] + bias[n + 0] + pos[prow + n + 0];
      o4.y = acc[i][half * 4 + 1] + bias[n + 1] + pos[prow + n + 1];
      o4.z = acc[i][half * 4 + 2] + bias[n + 2] + pos[prow + n + 2];
      o4.w = acc[i][half * 4 + 3] + bias[n + 3] + pos[prow + n + 3];
      *(float4*)&scene[row + n] = o4;
    }
  }
}

__global__ void scene_cls(const float* __restrict__ cls, const float* __restrict__ pos,
                          float* __restrict__ scene) {
  int b = blockIdx.x;
  for (int e = threadIdx.x; e < E_DIM; e += 256)
    scene[(size_t)b * NTOK * E_DIM + e] = cls[e] + pos[e];
}

__global__ __launch_bounds__(256) void ln_rows(const float* __restrict__ in, float* __restrict__ out) {
  __shared__ float red[256];
  int r = blockIdx.x, tid = threadIdx.x;
  const float* x = in + (size_t)r * E_DIM;
  float a0 = x[tid], a1 = x[tid + 256], a2 = x[tid + 512];
  float mean = block_reduce_sum(a0 + a1 + a2, red) * (1.f / 768.f);
  float d0 = a0 - mean, d1 = a1 - mean, d2 = a2 - mean;
  float var = block_reduce_sum(d0 * d0 + d1 * d1 + d2 * d2, red) * (1.f / 768.f);
  float rinv = rsqrtf(var + 1e-5f);
  float* o = out + (size_t)r * E_DIM;
  o[tid] = d0 * rinv; o[tid + 256] = d1 * rinv; o[tid + 512] = d2 * rinv;
}

__global__ __launch_bounds__(256) void tgt_init(
    const float* __restrict__ tmask, const float* __restrict__ W,
    const float* __restrict__ bias, const float* __restrict__ cls,
    const float* __restrict__ tpos, float* __restrict__ tq) {
  int b = blockIdx.x, tid = threadIdx.x;
  for (int e = tid; e < E_DIM; e += 256)
    tq[(size_t)(b * 2) * E_DIM + e] = cls[e] + tpos[e];
  const float* tm = tmask + (size_t)b * P2;
  for (int e = tid; e < E_DIM; e += 256) {
    const float* wr = W + (size_t)e * P2;
    float s = 0.f;
    for (int k = 0; k < P2; k += 4) {
      float4 w4 = *(const float4*)&wr[k];
      float4 t4 = *(const float4*)&tm[k];
      s += w4.x * t4.x + w4.y * t4.y + w4.z * t4.z + w4.w * t4.w;
    }
    tq[(size_t)(b * 2 + 1) * E_DIM + e] = s + bias[e] + tpos[E_DIM + e];
  }
}

__global__ void prep_m(const float* __restrict__ Wq, const float* __restrict__ Wk,
                       float* __restrict__ Mb) {
  int l = blockIdx.y;
  int idx = blockIdx.x * 256 + threadIdx.x;
  int d = idx >> 6, dp = idx & 63;
  const float* wq = Wq + l * 4096;
  const float* wk = Wk + l * 4096;
  float s = 0.f;
#pragma unroll 8
  for (int e = 0; e < 64; ++e) s += wq[e * 64 + d] * wk[e * 64 + dp];
  Mb[l * 4096 + idx] = s;
}

__global__ void prep_wvo(const float* __restrict__ Wv, const float* __restrict__ Wo,
                         float* __restrict__ Wvo) {
  int l = blockIdx.y;
  int idx = blockIdx.x * 256 + threadIdx.x;
  int ep = idx / 768, hd = idx % 768;
  int h = hd >> 6, d = hd & 63;
  const float* wv = Wv + (size_t)l * 4096;
  const float* wo = Wo + (size_t)l * 768 * 768 + (size_t)ep * 768 + h * 64;
  float s = 0.f;
#pragma unroll 8
  for (int ev = 0; ev < 64; ++ev) s += wv[ev * 64 + d] * wo[ev];
  Wvo[(size_t)l * 589824 + idx] = s;
}

// ---------------- attn with in-block q-LN+projection ----------------
// one block per (b,h). Computes its own qMg/qMb slice from tq (bit-identical
// op order to the old qln_qm), then flash attention over scene.
#define ACH 272
__global__ __launch_bounds__(256) void attn_flash_q(
    const float* __restrict__ tq, const float* __restrict__ Mb,
    const float* __restrict__ g1, const float* __restrict__ b1, int l,
    const float* __restrict__ ns, float* __restrict__ ctx) {
  __shared__ float red[256];
  __shared__ float qs[2][64];
  __shared__ float qg[2][64];
  __shared__ float qmb[2];
  __shared__ float sred[2][16];
  __shared__ float cred[2][16][64];
  int b = blockIdx.x / NHEADS;
  int h = blockIdx.x % NHEADS;
  int tid = threadIdx.x;
  const float* gl = g1 + l * E_DIM;
  const float* bl = b1 + l * E_DIM;
  int seg = h >> 2;                 // which 256-col segment holds this head
  int base = h * 64 - seg * 256;    // tid offset for d=0
  // q-LN for the two target rows (full-row stats, head-slice output)
  for (int r = 0; r < 2; ++r) {
    const float* x = tq + (size_t)(b * 2 + r) * E_DIM;
    float a0 = x[tid], a1 = x[tid + 256], a2 = x[tid + 512];
    float mean = block_reduce_sum(a0 + a1 + a2, red) * (1.f / 768.f);
    float d0 = a0 - mean, d1 = a1 - mean, d2 = a2 - mean;
    float var = block_reduce_sum(d0 * d0 + d1 * d1 + d2 * d2, red) * (1.f / 768.f);
    float rinv = rsqrtf(var + 1e-5f);
    float dv = (seg == 0) ? d0 : ((seg == 1) ? d1 : d2);
    if (tid >= base && tid < base + 64) {
      int d = tid - base;
      qs[r][d] = dv * rinv * gl[h * 64 + d] + bl[h * 64 + d];
    }
  }
  __syncthreads();
  // qm = q_h @ M ; fold gamma/scale into qg, beta into qmb
  const float inv_scale = rsqrtf(768.f);
  if (tid < 128) {
    int r = tid >> 6, dp = tid & 63;
    const float* M = Mb + l * 4096;
    float s = 0.f;
#pragma unroll 8
    for (int d = 0; d < 64; ++d) s += qs[r][d] * M[d * 64 + dp];
    qg[r][dp] = s * gl[h * 64 + dp] * inv_scale;
    red[tid] = s * bl[h * 64 + dp];
  }
  __syncthreads();
  if (tid < 2) {
    float a = 0.f;
    for (int dp = 0; dp < 64; ++dp) a += red[tid * 64 + dp];
    qmb[tid] = a * inv_scale;
  }
  __syncthreads();
  // ---- flash attention (body identical to proven attn_flash) ----
  int g = tid >> 4;
  int lane = tid & 15;
  int r0 = b * 2, r1 = r0 + 1;
  const float* nsb = ns + (size_t)b * NTOK * E_DIM + h * 64;
  float4 q0v = *(const float4*)&qg[0][lane * 4];
  float4 q1v = *(const float4*)&qg[1][lane * 4];
  float qb0 = qmb[0], qb1 = qmb[1];
  float m = -1e30f, s0 = 0.f, s1 = 0.f;
  float4 c0 = {0, 0, 0, 0}, c1 = {0, 0, 0, 0};
  float4 v[17];
  float e0a[17], e1a[17];
  for (int cb = 0; cb < NTOK; cb += ACH) {
    int ntk = NTOK - cb; if (ntk > ACH) ntk = ACH;
    int cnt = (ntk - g + 15) >> 4;
    float mloc = -1e30f;
#pragma unroll
    for (int i = 0; i < 17; ++i) {
      if (i < cnt) {
        int k = cb + g + (i << 4);
        float4 vv = *(const float4*)(nsb + (size_t)k * E_DIM + lane * 4);
        v[i] = vv;
        float p0 = vv.x * q0v.x + vv.y * q0v.y + vv.z * q0v.z + vv.w * q0v.w;
        float p1 = vv.x * q1v.x + vv.y * q1v.y + vv.z * q1v.z + vv.w * q1v.w;
#pragma unroll
        for (int off = 8; off; off >>= 1) {
          p0 += __shfl_xor(p0, off, 16);
          p1 += __shfl_xor(p1, off, 16);
        }
        float e0 = p0 + qb0, e1 = p1 + qb1;
        e0a[i] = e0; e1a[i] = e1;
        mloc = fmaxf(mloc, fmaxf(e0, e1));
      }
    }
    red[tid] = mloc;
    __syncthreads();
#pragma unroll
    for (int s = 128; s > 0; s >>= 1) {
      if (tid < s) red[tid] = fmaxf(red[tid], red[tid + s]);
      __syncthreads();
    }
    float mnew = fmaxf(m, red[0]);
    __syncthreads();
    if (mnew > m) {
      float f = expf(m - mnew);
      s0 *= f; s1 *= f;
      c0.x *= f; c0.y *= f; c0.z *= f; c0.w *= f;
      c1.x *= f; c1.y *= f; c1.z *= f; c1.w *= f;
      m = mnew;
    }
#pragma unroll
    for (int i = 0; i < 17; ++i) {
      if (i < cnt) {
        float p0 = expf(e0a[i] - m);
        float p1 = expf(e1a[i] - m);
        s0 += p0; s1 += p1;
        c0.x += p0 * v[i].x; c0.y += p0 * v[i].y; c0.z += p0 * v[i].z; c0.w += p0 * v[i].w;
        c1.x += p1 * v[i].x; c1.y += p1 * v[i].y; c1.z += p1 * v[i].z; c1.w += p1 * v[i].w;
      }
    }
  }
  if (lane == 0) { sred[0][g] = s0; sred[1][g] = s1; }
  *(float4*)&cred[0][g][lane * 4] = c0;
  *(float4*)&cred[1][g][lane * 4] = c1;
  __syncthreads();
  if (tid < 128) {
    int t = tid >> 6, dd = tid & 63;
    int o = h * 64 + dd;
    float stot = 0.f, cs = 0.f;
#pragma unroll
    for (int gg = 0; gg < 16; ++gg) { stot += sred[t][gg]; cs += cred[t][gg][dd]; }
    float inv = 1.f / stot;
    ctx[(size_t)(r0 + t) * E_DIM + o] = cs * inv * gl[o] + bl[o];
  }
}

// ---------------- out-proj + LN1 fused: 16 blocks x 4 rows ----------------
__global__ __launch_bounds__(256) void projln(
    const float* __restrict__ ctx, const float* __restrict__ Wvo_l,
    const float* __restrict__ bo_l, const float* __restrict__ tq,
    const float* __restrict__ gl, const float* __restrict__ bl,
    float* __restrict__ x) {
  __shared__ float cx[4][768];
  __shared__ float pr[4][768];
  __shared__ float red[256];
  int r0 = blockIdx.x * 4;
  int tid = threadIdx.x;
  int g = tid >> 4, lane = tid & 15;
  for (int i = tid; i < 4 * 768; i += 256) {
    int rr = i / 768, cc = i % 768;           // FIXED: was i>>9 / i&767 (wrong for 768)
    cx[rr][cc] = ctx[(size_t)(r0 + rr) * 768 + cc];
  }
  __syncthreads();
  for (int n = g; n < 768; n += 16) {
    const float* w = Wvo_l + (size_t)n * 768;
    float a0 = 0.f, a1 = 0.f, a2 = 0.f, a3 = 0.f;
    for (int k = lane * 4; k < 768; k += 64) {
      float4 wv = *(const float4*)(w + k);
      float4 v0 = *(const float4*)&cx[0][k];
      float4 v1 = *(const float4*)&cx[1][k];
      float4 v2 = *(const float4*)&cx[2][k];
      float4 v3 = *(const float4*)&cx[3][k];
      a0 += wv.x * v0.x + wv.y * v0.y + wv.z * v0.z + wv.w * v0.w;
      a1 += wv.x * v1.x + wv.y * v1.y + wv.z * v1.z + wv.w * v1.w;
      a2 += wv.x * v2.x + wv.y * v2.y + wv.z * v2.z + wv.w * v2.w;
      a3 += wv.x * v3.x + wv.y * v3.y + wv.z * v3.z + wv.w * v3.w;
    }
#pragma unroll
    for (int off = 8; off; off >>= 1) {
      a0 += __shfl_xor(a0, off, 16);
      a1 += __shfl_xor(a1, off, 16);
      a2 += __shfl_xor(a2, off, 16);
      a3 += __shfl_xor(a3, off, 16);
    }
    if (lane == 0) { pr[0][n] = a0; pr[1][n] = a1; pr[2][n] = a2; pr[3][n] = a3; }
  }
  __syncthreads();
  for (int r = 0; r < 4; ++r) {
    int row = r0 + r;
    float t0 = pr[r][tid] + bo_l[tid] + tq[(size_t)row * 768 + tid];
    float t1 = pr[r][tid + 256] + bo_l[tid + 256] + tq[(size_t)row * 768 + tid + 256];
    float t2 = pr[r][tid + 512] + bo_l[tid + 512] + tq[(size_t)row * 768 + tid + 512];
    float mean = block_reduce_sum(t0 + t1 + t2, red) * (1.f / 768.f);
    float d0 = t0 - mean, d1 = t1 - mean, d2 = t2 - mean;
    float var = block_reduce_sum(d0 * d0 + d1 * d1 + d2 * d2, red) * (1.f / 768.f);
    float rinv = rsqrtf(var + 1e-5f);
    x[(size_t)row * 768 + tid] = d0 * rinv * gl[tid] + bl[tid];
    x[(size_t)row * 768 + tid + 256] = d1 * rinv * gl[tid + 256] + bl[tid + 256];
    x[(size_t)row * 768 + tid + 512] = d2 * rinv * gl[tid + 512] + bl[tid + 512];
  }
}

// ---------------- skinny GEMM (M=64); optional bias(+relu) epilogue ----------------
__global__ __launch_bounds__(256) void skinny_part(
    const float* __restrict__ X, int K, const float* __restrict__ W,
    int kchunk, float* __restrict__ part, int N,
    const float* __restrict__ bias, int relu) {
  __shared__ float Xs[16][64];
  __shared__ float Ws[16][64];
  int tid = threadIdx.x;
  int n0 = blockIdx.x * 64;
  int s = blockIdx.y;
  int kbeg = s * kchunk;
  int lr = tid >> 2;
  int lk = (tid & 3) << 2;
  int ty = tid >> 4, tx = tid & 15;
  float acc[4][4] = {};
  for (int k0 = kbeg; k0 < kbeg + kchunk; k0 += 16) {
    float4 xv = *(const float4*)(X + (size_t)lr * K + k0 + lk);
    float4 wv = *(const float4*)(W + (size_t)(n0 + lr) * K + k0 + lk);
    __syncthreads();
    Xs[lk + 0][lr] = xv.x; Xs[lk + 1][lr] = xv.y; Xs[lk + 2][lr] = xv.z; Xs[lk + 3][lr] = xv.w;
    Ws[lk + 0][lr] = wv.x; Ws[lk + 1][lr] = wv.y; Ws[lk + 2][lr] = wv.z; Ws[lk + 3][lr] = wv.w;
    __syncthreads();
#pragma unroll
    for (int kk = 0; kk < 16; ++kk) {
      float4 a4 = *(const float4*)&Xs[kk][ty << 2];
      float4 b4 = *(const float4*)&Ws[kk][tx << 2];
      float av[4] = {a4.x, a4.y, a4.z, a4.w};
      float bv[4] = {b4.x, b4.y, b4.z, b4.w};
#pragma unroll
      for (int i = 0; i < 4; ++i)
#pragma unroll
        for (int j = 0; j < 4; ++j) acc[i][j] += av[i] * bv[j];
    }
  }
#pragma unroll
  for (int i = 0; i < 4; ++i) {
    int mm = (ty << 2) + i;
    float4 o4 = make_float4(acc[i][0], acc[i][1], acc[i][2], acc[i][3]);
    if (bias) {
      int n = n0 + (tx << 2);
      o4.x += bias[n + 0]; o4.y += bias[n + 1]; o4.z += bias[n + 2]; o4.w += bias[n + 3];
      if (relu) {
        o4.x = fmaxf(o4.x, 0.f); o4.y = fmaxf(o4.y, 0.f);
        o4.z = fmaxf(o4.z, 0.f); o4.w = fmaxf(o4.w, 0.f);
      }
    }
    *(float4*)&part[((size_t)s * 64 + mm) * N + n0 + (tx << 2)] = o4;
  }
}

// reduce partials + bias + residual + LN2 -> tq'; optional xm accumulation
__global__ __launch_bounds__(256) void reduce_ln(
    const float* __restrict__ part, int S, const float* __restrict__ bias,
    const float* __restrict__ res, const float* __restrict__ g,
    const float* __restrict__ bsh, float* __restrict__ out,
    float* __restrict__ xmean) {
  __shared__ float red[256];
  int m = blockIdx.x, tid = threadIdx.x;
  float t[3];
#pragma unroll
  for (int c = 0; c < 3; ++c) {
    int n = tid + c * 256;
    float s = 0.f;
    for (int i = 0; i < S; ++i) s += part[((size_t)i * 64 + m) * 768 + n];
    t[c] = s + bias[n] + res[(size_t)m * 768 + n];
  }
  float mean = block_reduce_sum(t[0] + t[1] + t[2], red) * (1.f / 768.f);
  float d0 = t[0] - mean, d1 = t[1] - mean, d2 = t[2] - mean;
  float var = block_reduce_sum(d0 * d0 + d1 * d1 + d2 * d2, red) * (1.f / 768.f);
  float rinv = rsqrtf(var + 1e-5f);
  float y0 = d0 * rinv * g[tid] + bsh[tid];
  float y1 = d1 * rinv * g[tid + 256] + bsh[tid + 256];
  float y2 = d2 * rinv * g[tid + 512] + bsh[tid + 512];
  out[(size_t)m * 768 + tid] = y0;
  out[(size_t)m * 768 + tid + 256] = y1;
  out[(size_t)m * 768 + tid + 512] = y2;
  if (xmean) {
    float* xr = xmean + (size_t)(m >> 1) * 768;
    atomicAdd(&xr[tid], 0.5f * y0);
    atomicAdd(&xr[tid + 256], 0.5f * y1);
    atomicAdd(&xr[tid + 512], 0.5f * y2);
  }
}

// head: logits row from 4 partials + bias, then top-5 one-hot
__global__ __launch_bounds__(256) void top5_from_parts(
    const float* __restrict__ part, const float* __restrict__ bias,
    float* __restrict__ out) {
  __shared__ float v[1024];
  __shared__ float bv[256];
  __shared__ int bi[256];
  int b = blockIdx.x, tid = threadIdx.x;
  for (int i = tid; i < 1024; i += 256) {
    float s = part[(size_t)(0 * 64 + b) * 1024 + i] + part[(size_t)(1 * 64 + b) * 1024 + i] +
              part[(size_t)(2 * 64 + b) * 1024 + i] + part[(size_t)(3 * 64 + b) * 1024 + i];
    v[i] = s + bias[i];
  }
  float* ob = out + (size_t)b * 5 * NTOK;
  for (int i = tid; i < 5 * NTOK; i += 256) ob[i] = 0.f;
  __syncthreads();
  for (int it = 0; it < 5; ++it) {
    float best = -1e38f;
    int bidx = 0x7fffffff;
    for (int i = tid; i < 1024; i += 256) {
      float x = v[i];
      if (x > best || (x == best && i < bidx)) { best = x; bidx = i; }
    }
    bv[tid] = best; bi[tid] = bidx;
    __syncthreads();
    for (int s = 128; s > 0; s >>= 1) {
      if (tid < s) {
        if (bv[tid + s] > bv[tid] || (bv[tid + s] == bv[tid] && bi[tid + s] < bi[tid])) {
          bv[tid] = bv[tid + s]; bi[tid] = bi[tid + s];
        }
      }
      __syncthreads();
    }
    if (tid == 0) {
      ob[it * NTOK + bi[0]] = 1.0f;
      v[bi[0]] = -1e38f;
    }
    __syncthreads();
  }
}

extern "C" void kernel_launch(void* const* d_in, const int* in_sizes, int n_in,
                              void* d_out, int out_size, void* d_ws, size_t ws_size,
                              hipStream_t stream) {
  const float* scene_masks = (const float*)d_in[0];
  const float* target_mask = (const float*)d_in[1];
  const float* emb_W = (const float*)d_in[2];
  const float* emb_b = (const float*)d_in[3];
  const float* class_embed = (const float*)d_in[4];
  const float* scene_pos = (const float*)d_in[5];
  const float* target_pos = (const float*)d_in[6];
  const float* ln1_g = (const float*)d_in[7];
  const float* ln1_b = (const float*)d_in[8];
  const float* ln2_g = (const float*)d_in[9];
  const float* ln2_b = (const float*)d_in[10];
  const float* Wq = (const float*)d_in[11];
  const float* Wk = (const float*)d_in[12];
  const float* Wv = (const float*)d_in[13];
  const float* Wo = (const float*)d_in[14];
  const float* bo = (const float*)d_in[15];
  const float* W1 = (const float*)d_in[16];
  const float* fb1 = (const float*)d_in[17];
  const float* W2 = (const float*)d_in[18];
  const float* fb2 = (const float*)d_in[19];
  const float* mlp_W = (const float*)d_in[20];
  const float* mlp_b = (const float*)d_in[21];
  float* out = (float*)d_out;

  float* ws = (float*)d_ws;
  float* scene = ws;                       // 25190400
  float* Mbuf = scene + 25190400;          // 49152
  float* Wvo = Mbuf + 49152;               // 7077888
  float* tq = Wvo + 7077888;               // 49152
  float* ctxf = tq + 49152;                // 49152
  float* xbuf = ctxf + 49152;              // 49152
  float* h1 = xbuf + 49152;                // 196608 (64x3072)
  float* xm = h1 + 196608;                 // 49152 (64x768, zeroed; rows>=32 stay 0)
  float* partA = xm + 49152;               // 786432

  // ---- setup ----
  embed_gemm<<<dim3(6, 256), 256, 0, stream>>>(scene_masks, emb_W, emb_b, scene_pos, scene);
  scene_cls<<<32, 256, 0, stream>>>(class_embed, scene_pos, scene);
  ln_rows<<<32 * NTOK, 256, 0, stream>>>(scene, scene);
  tgt_init<<<32, 256, 0, stream>>>(target_mask, emb_W, emb_b, class_embed, target_pos, tq);
  prep_m<<<dim3(16, 12), 256, 0, stream>>>(Wq, Wk, Mbuf);
  prep_wvo<<<dim3(2304, 12), 256, 0, stream>>>(Wv, Wo, Wvo);
  hipMemsetAsync(xm, 0, 49152 * sizeof(float), stream);

  // ---- 12 transformer blocks, 5 launches each ----
  for (int l = 0; l < LAYERS; ++l) {
    // 1. attention with in-block q-LN+projection
    attn_flash_q<<<32 * NHEADS, 256, 0, stream>>>(tq, Mbuf, ln1_g, ln1_b, l, scene, ctxf);
    // 2. out-proj + LN1 -> x
    projln<<<16, 256, 0, stream>>>(ctxf, Wvo + (size_t)l * 589824, bo + l * 768,
                                   tq, ln1_g + l * 768, ln1_b + l * 768, xbuf);
    // 3. FF1 full-K, fused bias+relu -> h1
    skinny_part<<<dim3(48, 1), 256, 0, stream>>>(xbuf, 768, W1 + (size_t)l * FF_DIM * 768,
                                                 768, h1, FF_DIM, fb1 + l * FF_DIM, 1);
    // 4. FF2 partials: 12 n-tiles x 4 k-chunks(768)
    skinny_part<<<dim3(12, 4), 256, 0, stream>>>(h1, FF_DIM, W2 + (size_t)l * 768 * FF_DIM,
                                                 768, partA, 768, nullptr, 0);
    // 5. tq' = LN2(sum + b2 + x); layer 11 also accumulates xm
    reduce_ln<<<64, 256, 0, stream>>>(partA, 4, fb2 + l * 768, xbuf,
                                      ln2_g + l * 768, ln2_b + l * 768, tq,
                                      (l == LAYERS - 1) ? xm : nullptr);
  }

  // ---- head ----
  skinny_part<<<dim3(16, 4), 256, 0, stream>>>(xm, 768, mlp_W, 192, partA, 1024, nullptr, 0);
  top5_from_parts<<<32, 256, 0, stream>>>(partA, mlp_b, out);
}

// Round 11
// 1931.021 us; speedup vs baseline: 3.1671x; 2.6492x over previous
//
#include <hip/hip_runtime.h>
#include <math.h>

#define E_DIM 768
#define NTOK 1025
#define B_DIM 32
#define NHEADS 12
#define HDIM 64
#define LAYERS 12
#define FF_DIM 3072
#define P2 576

// ---------------- helpers ----------------
__device__ __forceinline__ float block_reduce_sum(float v, float* red) {
  int tid = threadIdx.x;
  red[tid] = v;
  __syncthreads();
#pragma unroll
  for (int s = 128; s > 0; s >>= 1) {
    if (tid < s) red[tid] += red[tid + s];
    __syncthreads();
  }
  float r = red[0];
  __syncthreads();
  return r;
}

// ---------------- embed GEMM: 128x128 tile, 8x8 acc/thread ----------------
__global__ __launch_bounds__(256) void embed_gemm(
    const float* __restrict__ A, const float* __restrict__ W,
    const float* __restrict__ bias, const float* __restrict__ pos,
    float* __restrict__ scene) {
  __shared__ float Xs[16][132];
  __shared__ float Ws[16][132];
  int tid = threadIdx.x;
  int n0 = blockIdx.x * 128;
  int m0 = blockIdx.y * 128;
  int lr = tid >> 2;
  int lk = (tid & 3) << 2;
  int ty = tid >> 4, tx = tid & 15;
  float acc[8][8] = {};
  for (int k0 = 0; k0 < P2; k0 += 16) {
    float4 x0 = *(const float4*)(A + (size_t)(m0 + lr) * P2 + k0 + lk);
    float4 x1 = *(const float4*)(A + (size_t)(m0 + 64 + lr) * P2 + k0 + lk);
    float4 w0 = *(const float4*)(W + (size_t)(n0 + lr) * P2 + k0 + lk);
    float4 w1 = *(const float4*)(W + (size_t)(n0 + 64 + lr) * P2 + k0 + lk);
    __syncthreads();
    Xs[lk + 0][lr] = x0.x; Xs[lk + 1][lr] = x0.y; Xs[lk + 2][lr] = x0.z; Xs[lk + 3][lr] = x0.w;
    Xs[lk + 0][64 + lr] = x1.x; Xs[lk + 1][64 + lr] = x1.y; Xs[lk + 2][64 + lr] = x1.z; Xs[lk + 3][64 + lr] = x1.w;
    Ws[lk + 0][lr] = w0.x; Ws[lk + 1][lr] = w0.y; Ws[lk + 2][lr] = w0.z; Ws[lk + 3][lr] = w0.w;
    Ws[lk + 0][64 + lr] = w1.x; Ws[lk + 1][64 + lr] = w1.y; Ws[lk + 2][64 + lr] = w1.z; Ws[lk + 3][64 + lr] = w1.w;
    __syncthreads();
#pragma unroll
    for (int kk = 0; kk < 16; ++kk) {
      float4 a0 = *(const float4*)&Xs[kk][ty << 2];
      float4 a1 = *(const float4*)&Xs[kk][64 + (ty << 2)];
      float4 b0 = *(const float4*)&Ws[kk][tx << 2];
      float4 b1 = *(const float4*)&Ws[kk][64 + (tx << 2)];
      float av[8] = {a0.x, a0.y, a0.z, a0.w, a1.x, a1.y, a1.z, a1.w};
      float bv[8] = {b0.x, b0.y, b0.z, b0.w, b1.x, b1.y, b1.z, b1.w};
#pragma unroll
      for (int i = 0; i < 8; ++i)
#pragma unroll
        for (int j = 0; j < 8; ++j) acc[i][j] += av[i] * bv[j];
    }
  }
#pragma unroll
  for (int i = 0; i < 8; ++i) {
    int mloc = (i < 4) ? ((ty << 2) + i) : (64 + (ty << 2) + i - 4);
    int m = m0 + mloc;
    int b = m >> 10, nt = m & 1023;
    size_t row = ((size_t)b * NTOK + 1 + nt) * E_DIM;
    size_t prow = (size_t)(1 + nt) * E_DIM;
#pragma unroll
    for (int half = 0; half < 2; ++half) {
      int n = n0 + half * 64 + (tx << 2);
      float4 o4;
      o4.x = acc[i][half * 4 + 0] + bias[n + 0] + pos[prow + n + 0];
      o4.y = acc[i][half * 4 + 1] + bias[n + 1] + pos[prow + n + 1];
      o4.z = acc[i][half * 4 + 2] + bias[n + 2] + pos[prow + n + 2];
      o4.w = acc[i][half * 4 + 3] + bias[n + 3] + pos[prow + n + 3];
      *(float4*)&scene[row + n] = o4;
    }
  }
}

__global__ void scene_cls(const float* __restrict__ cls, const float* __restrict__ pos,
                          float* __restrict__ scene) {
  int b = blockIdx.x;
  for (int e = threadIdx.x; e < E_DIM; e += 256)
    scene[(size_t)b * NTOK * E_DIM + e] = cls[e] + pos[e];
}

__global__ __launch_bounds__(256) void ln_rows(const float* __restrict__ in, float* __restrict__ out) {
  __shared__ float red[256];
  int r = blockIdx.x, tid = threadIdx.x;
  const float* x = in + (size_t)r * E_DIM;
  float a0 = x[tid], a1 = x[tid + 256], a2 = x[tid + 512];
  float mean = block_reduce_sum(a0 + a1 + a2, red) * (1.f / 768.f);
  float d0 = a0 - mean, d1 = a1 - mean, d2 = a2 - mean;
  float var = block_reduce_sum(d0 * d0 + d1 * d1 + d2 * d2, red) * (1.f / 768.f);
  float rinv = rsqrtf(var + 1e-5f);
  float* o = out + (size_t)r * E_DIM;
  o[tid] = d0 * rinv; o[tid + 256] = d1 * rinv; o[tid + 512] = d2 * rinv;
}

__global__ __launch_bounds__(256) void tgt_init(
    const float* __restrict__ tmask, const float* __restrict__ W,
    const float* __restrict__ bias, const float* __restrict__ cls,
    const float* __restrict__ tpos, float* __restrict__ tq) {
  int b = blockIdx.x, tid = threadIdx.x;
  for (int e = tid; e < E_DIM; e += 256)
    tq[(size_t)(b * 2) * E_DIM + e] = cls[e] + tpos[e];
  const float* tm = tmask + (size_t)b * P2;
  for (int e = tid; e < E_DIM; e += 256) {
    const float* wr = W + (size_t)e * P2;
    float s = 0.f;
    for (int k = 0; k < P2; k += 4) {
      float4 w4 = *(const float4*)&wr[k];
      float4 t4 = *(const float4*)&tm[k];
      s += w4.x * t4.x + w4.y * t4.y + w4.z * t4.z + w4.w * t4.w;
    }
    tq[(size_t)(b * 2 + 1) * E_DIM + e] = s + bias[e] + tpos[E_DIM + e];
  }
}

__global__ void prep_m(const float* __restrict__ Wq, const float* __restrict__ Wk,
                       float* __restrict__ Mb) {
  int l = blockIdx.y;
  int idx = blockIdx.x * 256 + threadIdx.x;
  int d = idx >> 6, dp = idx & 63;
  const float* wq = Wq + l * 4096;
  const float* wk = Wk + l * 4096;
  float s = 0.f;
#pragma unroll 8
  for (int e = 0; e < 64; ++e) s += wq[e * 64 + d] * wk[e * 64 + dp];
  Mb[l * 4096 + idx] = s;
}

__global__ void prep_wvo(const float* __restrict__ Wv, const float* __restrict__ Wo,
                         float* __restrict__ Wvo) {
  int l = blockIdx.y;
  int idx = blockIdx.x * 256 + threadIdx.x;
  int ep = idx / 768, hd = idx % 768;
  int h = hd >> 6, d = hd & 63;
  const float* wv = Wv + (size_t)l * 4096;
  const float* wo = Wo + (size_t)l * 768 * 768 + (size_t)ep * 768 + h * 64;
  float s = 0.f;
#pragma unroll 8
  for (int ev = 0; ev < 64; ++ev) s += wv[ev * 64 + d] * wo[ev];
  Wvo[(size_t)l * 589824 + idx] = s;
}

// ---------------- attn with in-block q-LN+projection (validated r10) ----------------
#define ACH 272
__global__ __launch_bounds__(256) void attn_flash_q(
    const float* __restrict__ tq, const float* __restrict__ Mb,
    const float* __restrict__ g1, const float* __restrict__ b1, int l,
    const float* __restrict__ ns, float* __restrict__ ctx) {
  __shared__ float red[256];
  __shared__ float qs[2][64];
  __shared__ float qg[2][64];
  __shared__ float qmb[2];
  __shared__ float sred[2][16];
  __shared__ float cred[2][16][64];
  int b = blockIdx.x / NHEADS;
  int h = blockIdx.x % NHEADS;
  int tid = threadIdx.x;
  const float* gl = g1 + l * E_DIM;
  const float* bl = b1 + l * E_DIM;
  int seg = h >> 2;
  int base = h * 64 - seg * 256;
  for (int r = 0; r < 2; ++r) {
    const float* x = tq + (size_t)(b * 2 + r) * E_DIM;
    float a0 = x[tid], a1 = x[tid + 256], a2 = x[tid + 512];
    float mean = block_reduce_sum(a0 + a1 + a2, red) * (1.f / 768.f);
    float d0 = a0 - mean, d1 = a1 - mean, d2 = a2 - mean;
    float var = block_reduce_sum(d0 * d0 + d1 * d1 + d2 * d2, red) * (1.f / 768.f);
    float rinv = rsqrtf(var + 1e-5f);
    float dv = (seg == 0) ? d0 : ((seg == 1) ? d1 : d2);
    if (tid >= base && tid < base + 64) {
      int d = tid - base;
      qs[r][d] = dv * rinv * gl[h * 64 + d] + bl[h * 64 + d];
    }
  }
  __syncthreads();
  const float inv_scale = rsqrtf(768.f);
  if (tid < 128) {
    int r = tid >> 6, dp = tid & 63;
    const float* M = Mb + l * 4096;
    float s = 0.f;
#pragma unroll 8
    for (int d = 0; d < 64; ++d) s += qs[r][d] * M[d * 64 + dp];
    qg[r][dp] = s * gl[h * 64 + dp] * inv_scale;
    red[tid] = s * bl[h * 64 + dp];
  }
  __syncthreads();
  if (tid < 2) {
    float a = 0.f;
    for (int dp = 0; dp < 64; ++dp) a += red[tid * 64 + dp];
    qmb[tid] = a * inv_scale;
  }
  __syncthreads();
  int g = tid >> 4;
  int lane = tid & 15;
  int r0 = b * 2, r1 = r0 + 1;
  const float* nsb = ns + (size_t)b * NTOK * E_DIM + h * 64;
  float4 q0v = *(const float4*)&qg[0][lane * 4];
  float4 q1v = *(const float4*)&qg[1][lane * 4];
  float qb0 = qmb[0], qb1 = qmb[1];
  float m = -1e30f, s0 = 0.f, s1 = 0.f;
  float4 c0 = {0, 0, 0, 0}, c1 = {0, 0, 0, 0};
  float4 v[17];
  float e0a[17], e1a[17];
  for (int cb = 0; cb < NTOK; cb += ACH) {
    int ntk = NTOK - cb; if (ntk > ACH) ntk = ACH;
    int cnt = (ntk - g + 15) >> 4;
    float mloc = -1e30f;
#pragma unroll
    for (int i = 0; i < 17; ++i) {
      if (i < cnt) {
        int k = cb + g + (i << 4);
        float4 vv = *(const float4*)(nsb + (size_t)k * E_DIM + lane * 4);
        v[i] = vv;
        float p0 = vv.x * q0v.x + vv.y * q0v.y + vv.z * q0v.z + vv.w * q0v.w;
        float p1 = vv.x * q1v.x + vv.y * q1v.y + vv.z * q1v.z + vv.w * q1v.w;
#pragma unroll
        for (int off = 8; off; off >>= 1) {
          p0 += __shfl_xor(p0, off, 16);
          p1 += __shfl_xor(p1, off, 16);
        }
        float e0 = p0 + qb0, e1 = p1 + qb1;
        e0a[i] = e0; e1a[i] = e1;
        mloc = fmaxf(mloc, fmaxf(e0, e1));
      }
    }
    red[tid] = mloc;
    __syncthreads();
#pragma unroll
    for (int s = 128; s > 0; s >>= 1) {
      if (tid < s) red[tid] = fmaxf(red[tid], red[tid + s]);
      __syncthreads();
    }
    float mnew = fmaxf(m, red[0]);
    __syncthreads();
    if (mnew > m) {
      float f = expf(m - mnew);
      s0 *= f; s1 *= f;
      c0.x *= f; c0.y *= f; c0.z *= f; c0.w *= f;
      c1.x *= f; c1.y *= f; c1.z *= f; c1.w *= f;
      m = mnew;
    }
#pragma unroll
    for (int i = 0; i < 17; ++i) {
      if (i < cnt) {
        float p0 = expf(e0a[i] - m);
        float p1 = expf(e1a[i] - m);
        s0 += p0; s1 += p1;
        c0.x += p0 * v[i].x; c0.y += p0 * v[i].y; c0.z += p0 * v[i].z; c0.w += p0 * v[i].w;
        c1.x += p1 * v[i].x; c1.y += p1 * v[i].y; c1.z += p1 * v[i].z; c1.w += p1 * v[i].w;
      }
    }
  }
  if (lane == 0) { sred[0][g] = s0; sred[1][g] = s1; }
  *(float4*)&cred[0][g][lane * 4] = c0;
  *(float4*)&cred[1][g][lane * 4] = c1;
  __syncthreads();
  if (tid < 128) {
    int t = tid >> 6, dd = tid & 63;
    int o = h * 64 + dd;
    float stot = 0.f, cs = 0.f;
#pragma unroll
    for (int gg = 0; gg < 16; ++gg) { stot += sred[t][gg]; cs += cred[t][gg][dd]; }
    float inv = 1.f / stot;
    ctx[(size_t)(r0 + t) * E_DIM + o] = cs * inv * gl[o] + bl[o];
  }
}

// ---------------- skinny GEMM (M=64) partial over k-chunk (r6-proven) ----------------
__global__ __launch_bounds__(256) void skinny_part(
    const float* __restrict__ X, int K, const float* __restrict__ W,
    int kchunk, float* __restrict__ part, int N) {
  __shared__ float Xs[16][64];
  __shared__ float Ws[16][64];
  int tid = threadIdx.x;
  int n0 = blockIdx.x * 64;
  int s = blockIdx.y;
  int kbeg = s * kchunk;
  int lr = tid >> 2;
  int lk = (tid & 3) << 2;
  int ty = tid >> 4, tx = tid & 15;
  float acc[4][4] = {};
  for (int k0 = kbeg; k0 < kbeg + kchunk; k0 += 16) {
    float4 xv = *(const float4*)(X + (size_t)lr * K + k0 + lk);
    float4 wv = *(const float4*)(W + (size_t)(n0 + lr) * K + k0 + lk);
    __syncthreads();
    Xs[lk + 0][lr] = xv.x; Xs[lk + 1][lr] = xv.y; Xs[lk + 2][lr] = xv.z; Xs[lk + 3][lr] = xv.w;
    Ws[lk + 0][lr] = wv.x; Ws[lk + 1][lr] = wv.y; Ws[lk + 2][lr] = wv.z; Ws[lk + 3][lr] = wv.w;
    __syncthreads();
#pragma unroll
    for (int kk = 0; kk < 16; ++kk) {
      float4 a4 = *(const float4*)&Xs[kk][ty << 2];
      float4 b4 = *(const float4*)&Ws[kk][tx << 2];
      float av[4] = {a4.x, a4.y, a4.z, a4.w};
      float bv[4] = {b4.x, b4.y, b4.z, b4.w};
#pragma unroll
      for (int i = 0; i < 4; ++i)
#pragma unroll
        for (int j = 0; j < 4; ++j) acc[i][j] += av[i] * bv[j];
    }
  }
#pragma unroll
  for (int i = 0; i < 4; ++i) {
    int mm = (ty << 2) + i;
    float4 o4 = make_float4(acc[i][0], acc[i][1], acc[i][2], acc[i][3]);
    *(float4*)&part[((size_t)s * 64 + mm) * N + n0 + (tx << 2)] = o4;
  }
}

// FF2 skinny: X = relu(sum_{s<4} part1[s] + b1) computed inline (K=3072) (r6-proven)
__global__ __launch_bounds__(256) void skinny_h1_part(
    const float* __restrict__ part1, const float* __restrict__ b1,
    const float* __restrict__ W, int kchunk, float* __restrict__ part2) {
  __shared__ float Xs[16][64];
  __shared__ float Ws[16][64];
  const int K = 3072, N = 768;
  int tid = threadIdx.x;
  int n0 = blockIdx.x * 64;
  int s = blockIdx.y;
  int kbeg = s * kchunk;
  int lr = tid >> 2;
  int lk = (tid & 3) << 2;
  int ty = tid >> 4, tx = tid & 15;
  float acc[4][4] = {};
  for (int k0 = kbeg; k0 < kbeg + kchunk; k0 += 16) {
    float4 x0 = *(const float4*)(part1 + (size_t)lr * K + k0 + lk);
    float4 x1 = *(const float4*)(part1 + (size_t)(64 + lr) * K + k0 + lk);
    float4 x2 = *(const float4*)(part1 + (size_t)(128 + lr) * K + k0 + lk);
    float4 x3 = *(const float4*)(part1 + (size_t)(192 + lr) * K + k0 + lk);
    float4 bb = *(const float4*)(b1 + k0 + lk);
    float4 xv;
    xv.x = fmaxf(x0.x + x1.x + x2.x + x3.x + bb.x, 0.f);
    xv.y = fmaxf(x0.y + x1.y + x2.y + x3.y + bb.y, 0.f);
    xv.z = fmaxf(x0.z + x1.z + x2.z + x3.z + bb.z, 0.f);
    xv.w = fmaxf(x0.w + x1.w + x2.w + x3.w + bb.w, 0.f);
    float4 wv = *(const float4*)(W + (size_t)(n0 + lr) * K + k0 + lk);
    __syncthreads();
    Xs[lk + 0][lr] = xv.x; Xs[lk + 1][lr] = xv.y; Xs[lk + 2][lr] = xv.z; Xs[lk + 3][lr] = xv.w;
    Ws[lk + 0][lr] = wv.x; Ws[lk + 1][lr] = wv.y; Ws[lk + 2][lr] = wv.z; Ws[lk + 3][lr] = wv.w;
    __syncthreads();
#pragma unroll
    for (int kk = 0; kk < 16; ++kk) {
      float4 a4 = *(const float4*)&Xs[kk][ty << 2];
      float4 b4 = *(const float4*)&Ws[kk][tx << 2];
      float av[4] = {a4.x, a4.y, a4.z, a4.w};
      float bv[4] = {b4.x, b4.y, b4.z, b4.w};
#pragma unroll
      for (int i = 0; i < 4; ++i)
#pragma unroll
        for (int j = 0; j < 4; ++j) acc[i][j] += av[i] * bv[j];
    }
  }
#pragma unroll
  for (int i = 0; i < 4; ++i) {
    int mm = (ty << 2) + i;
    float4 o4 = make_float4(acc[i][0], acc[i][1], acc[i][2], acc[i][3]);
    *(float4*)&part2[((size_t)s * 64 + mm) * N + n0 + (tx << 2)] = o4;
  }
}

// reduce partials + bias + residual + LN; optional xm accumulation (validated r10)
__global__ __launch_bounds__(256) void reduce_ln(
    const float* __restrict__ part, int S, const float* __restrict__ bias,
    const float* __restrict__ res, const float* __restrict__ g,
    const float* __restrict__ bsh, float* __restrict__ out,
    float* __restrict__ xmean) {
  __shared__ float red[256];
  int m = blockIdx.x, tid = threadIdx.x;
  float t[3];
#pragma unroll
  for (int c = 0; c < 3; ++c) {
    int n = tid + c * 256;
    float s = 0.f;
    for (int i = 0; i < S; ++i) s += part[((size_t)i * 64 + m) * 768 + n];
    t[c] = s + bias[n] + res[(size_t)m * 768 + n];
  }
  float mean = block_reduce_sum(t[0] + t[1] + t[2], red) * (1.f / 768.f);
  float d0 = t[0] - mean, d1 = t[1] - mean, d2 = t[2] - mean;
  float var = block_reduce_sum(d0 * d0 + d1 * d1 + d2 * d2, red) * (1.f / 768.f);
  float rinv = rsqrtf(var + 1e-5f);
  float y0 = d0 * rinv * g[tid] + bsh[tid];
  float y1 = d1 * rinv * g[tid + 256] + bsh[tid + 256];
  float y2 = d2 * rinv * g[tid + 512] + bsh[tid + 512];
  out[(size_t)m * 768 + tid] = y0;
  out[(size_t)m * 768 + tid + 256] = y1;
  out[(size_t)m * 768 + tid + 512] = y2;
  if (xmean) {
    float* xr = xmean + (size_t)(m >> 1) * 768;
    atomicAdd(&xr[tid], 0.5f * y0);
    atomicAdd(&xr[tid + 256], 0.5f * y1);
    atomicAdd(&xr[tid + 512], 0.5f * y2);
  }
}

// head: logits row from 4 partials + bias, then top-5 one-hot (r6-proven)
__global__ __launch_bounds__(256) void top5_from_parts(
    const float* __restrict__ part, const float* __restrict__ bias,
    float* __restrict__ out) {
  __shared__ float v[1024];
  __shared__ float bv[256];
  __shared__ int bi[256];
  int b = blockIdx.x, tid = threadIdx.x;
  for (int i = tid; i < 1024; i += 256) {
    float s = part[(size_t)(0 * 64 + b) * 1024 + i] + part[(size_t)(1 * 64 + b) * 1024 + i] +
              part[(size_t)(2 * 64 + b) * 1024 + i] + part[(size_t)(3 * 64 + b) * 1024 + i];
    v[i] = s + bias[i];
  }
  float* ob = out + (size_t)b * 5 * NTOK;
  for (int i = tid; i < 5 * NTOK; i += 256) ob[i] = 0.f;
  __syncthreads();
  for (int it = 0; it < 5; ++it) {
    float best = -1e38f;
    int bidx = 0x7fffffff;
    for (int i = tid; i < 1024; i += 256) {
      float x = v[i];
      if (x > best || (x == best && i < bidx)) { best = x; bidx = i; }
    }
    bv[tid] = best; bi[tid] = bidx;
    __syncthreads();
    for (int s = 128; s > 0; s >>= 1) {
      if (tid < s) {
        if (bv[tid + s] > bv[tid] || (bv[tid + s] == bv[tid] && bi[tid + s] < bi[tid])) {
          bv[tid] = bv[tid + s]; bi[tid] = bi[tid + s];
        }
      }
      __syncthreads();
    }
    if (tid == 0) {
      ob[it * NTOK + bi[0]] = 1.0f;
      v[bi[0]] = -1e38f;
    }
    __syncthreads();
  }
}

extern "C" void kernel_launch(void* const* d_in, const int* in_sizes, int n_in,
                              void* d_out, int out_size, void* d_ws, size_t ws_size,
                              hipStream_t stream) {
  const float* scene_masks = (const float*)d_in[0];
  const float* target_mask = (const float*)d_in[1];
  const float* emb_W = (const float*)d_in[2];
  const float* emb_b = (const float*)d_in[3];
  const float* class_embed = (const float*)d_in[4];
  const float* scene_pos = (const float*)d_in[5];
  const float* target_pos = (const float*)d_in[6];
  const float* ln1_g = (const float*)d_in[7];
  const float* ln1_b = (const float*)d_in[8];
  const float* ln2_g = (const float*)d_in[9];
  const float* ln2_b = (const float*)d_in[10];
  const float* Wq = (const float*)d_in[11];
  const float* Wk = (const float*)d_in[12];
  const float* Wv = (const float*)d_in[13];
  const float* Wo = (const float*)d_in[14];
  const float* bo = (const float*)d_in[15];
  const float* W1 = (const float*)d_in[16];
  const float* fb1 = (const float*)d_in[17];
  const float* W2 = (const float*)d_in[18];
  const float* fb2 = (const float*)d_in[19];
  const float* mlp_W = (const float*)d_in[20];
  const float* mlp_b = (const float*)d_in[21];
  float* out = (float*)d_out;

  float* ws = (float*)d_ws;
  float* scene = ws;                       // 25190400
  float* Mbuf = scene + 25190400;          // 49152
  float* Wvo = Mbuf + 49152;               // 7077888
  float* tq = Wvo + 7077888;               // 49152
  float* ctxf = tq + 49152;                // 49152
  float* xbuf = ctxf + 49152;              // 49152
  float* xm = xbuf + 49152;                // 49152 (64x768, zeroed; rows>=32 stay 0)
  float* partA = xm + 49152;               // 786432 (16x64x768 max)
  float* partB = partA + 786432;           // 786432 (4x64x3072)

  // ---- setup ----
  embed_gemm<<<dim3(6, 256), 256, 0, stream>>>(scene_masks, emb_W, emb_b, scene_pos, scene);
  scene_cls<<<32, 256, 0, stream>>>(class_embed, scene_pos, scene);
  ln_rows<<<32 * NTOK, 256, 0, stream>>>(scene, scene);
  tgt_init<<<32, 256, 0, stream>>>(target_mask, emb_W, emb_b, class_embed, target_pos, tq);
  prep_m<<<dim3(16, 12), 256, 0, stream>>>(Wq, Wk, Mbuf);
  prep_wvo<<<dim3(2304, 12), 256, 0, stream>>>(Wv, Wo, Wvo);
  hipMemsetAsync(xm, 0, 49152 * sizeof(float), stream);

  // ---- 12 transformer blocks, 6 launches each (r6 structure + fused-q attn) ----
  for (int l = 0; l < LAYERS; ++l) {
    // 1. attention with in-block q-LN+projection
    attn_flash_q<<<32 * NHEADS, 256, 0, stream>>>(tq, Mbuf, ln1_g, ln1_b, l, scene, ctxf);
    // 2. out-proj partials: 12 n-tiles x 8 k-chunks(96) -> partA
    skinny_part<<<dim3(12, 8), 256, 0, stream>>>(ctxf, 768, Wvo + (size_t)l * 589824, 96, partA, 768);
    // 3. x = LN1(sum + bo + tq)
    reduce_ln<<<64, 256, 0, stream>>>(partA, 8, bo + l * 768, tq,
                                      ln1_g + l * 768, ln1_b + l * 768, xbuf, nullptr);
    // 4. FF1 partials (no bias/relu; folded into FF2): 48 n-tiles x 4 k-chunks(192) -> partB
    skinny_part<<<dim3(48, 4), 256, 0, stream>>>(xbuf, 768, W1 + (size_t)l * FF_DIM * 768, 192, partB, FF_DIM);
    // 5. FF2 with inline h1 = relu(sum parts + b1): 12 n-tiles x 16 k-chunks(192) -> partA
    skinny_h1_part<<<dim3(12, 16), 256, 0, stream>>>(partB, fb1 + l * FF_DIM,
                                                     W2 + (size_t)l * 768 * FF_DIM, 192, partA);
    // 6. tq' = LN2(sum + b2 + x); layer 11 also accumulates xm
    reduce_ln<<<64, 256, 0, stream>>>(partA, 16, fb2 + l * 768, xbuf,
                                      ln2_g + l * 768, ln2_b + l * 768, tq,
                                      (l == LAYERS - 1) ? xm : nullptr);
  }

  // ---- head ----
  skinny_part<<<dim3(16, 4), 256, 0, stream>>>(xm, 768, mlp_W, 192, partA, 1024);
  top5_from_parts<<<32, 256, 0, stream>>>(partA, mlp_b, out);
}